// Round 8
// baseline (388.580 us; speedup 1.0000x reference)
//
#include <hip/hip_runtime.h>

#define NB 16
#define NN 2048
#define NP 512
#define NS 32
#define NC 64

typedef _Float16 f16x8 __attribute__((ext_vector_type(8)));
typedef _Float16 f16x4 __attribute__((ext_vector_type(4)));
typedef float f32x4 __attribute__((ext_vector_type(4)));
typedef float f32x2 __attribute__((ext_vector_type(2)));

// d2 with explicit rounding (no FMA contraction) to bit-match the reference
__device__ __forceinline__ float sqdist(float dx, float dy, float dz) {
  return __fadd_rn(__fadd_rn(__fmul_rn(dx, dx), __fmul_rn(dy, dy)), __fmul_rn(dz, dz));
}

// packed f32 add/mul via inline asm: separate mul and add instructions, so the
// compiler can never contract them into FMA -> bit-exact vs the reference.
__device__ __forceinline__ f32x2 pk_add(f32x2 a, f32x2 b) {
  f32x2 d;
  asm("v_pk_add_f32 %0, %1, %2" : "=v"(d) : "v"(a), "v"(b));
  return d;
}
__device__ __forceinline__ f32x2 pk_mul(f32x2 a, f32x2 b) {
  f32x2 d;
  asm("v_pk_mul_f32 %0, %1, %2" : "=v"(d) : "v"(a), "v"(b));
  return d;
}

template <int CTRL>
__device__ __forceinline__ float dppmaxf(float m) {
  int t = __builtin_amdgcn_update_dpp(0, __float_as_int(m), CTRL, 0xf, 0xf, true);
  return fmaxf(m, __int_as_float(t));  // 0-fill safe: all values >= 0
}

// ---------------------------------------------------------------------------
// Fused front kernel: block roles by blockIdx.x
//   [0,16)    : FPS for batch b = blockIdx.x        (256 thr = 4 waves)
//   [16,528)  : prep transpose tile (b, n0)          (featF f16 + xyzT)
//   528       : weight f16 conversion
// FPS: 4 waves x 8 pts/lane. Packed-f32 exact update; value wave-max via
// 6-step DPP; index via 8 ballots + scalar first-set scan (first-occurrence
// = min n exact); cross-wave merge via one 32B LDS read + 3 lex compares;
// centroid broadcast via uniform ds_read_b128 from LDS xyz copy. Centroids
// stored directly to global from t==0 (off critical path).
// ---------------------------------------------------------------------------
__global__ __launch_bounds__(256, 1) void front_kernel(
    const float* __restrict__ xyz, const float* __restrict__ feat,
    const float* __restrict__ W1, const float* __restrict__ W2, const float* __restrict__ W3,
    float* __restrict__ newxyz, _Float16* __restrict__ featF, float* __restrict__ xyzT,
    _Float16* __restrict__ W1f, _Float16* __restrict__ W2f, _Float16* __restrict__ W3f) {
  __shared__ __align__(16) char sm[32896];
  const int bid = blockIdx.x;
  const int t = threadIdx.x;

  if (bid >= 16) {
    if (bid == 528) {
      // ---- wconv role ----
      for (int i = t; i < 256 * 128; i += 256) {
        if (i < 64 * 96) {
          int o = i / 96, k = i - o * 96;
          float v = (k < 64) ? W1[o * 67 + 3 + k] : ((k < 67) ? W1[o * 67 + (k - 64)] : 0.f);
          W1f[i] = (_Float16)v;
        }
        if (i < 128 * 64) W2f[i] = (_Float16)W2[i];
        W3f[i] = (_Float16)W3[i];
      }
      return;
    }
    // ---- prep role ----
    float(*tile)[65] = (float(*)[65])sm;
    const int pb = bid - 16;
    const int b = pb >> 5;
    const int n0 = (pb & 31) * 64;
    const int g = t >> 6, l = t & 63;
    if (g == 0) {
      int n = n0 + l;
      float4 q;
      q.x = xyz[(size_t)b * 3 * NN + n];
      q.y = xyz[(size_t)b * 3 * NN + NN + n];
      q.z = xyz[(size_t)b * 3 * NN + 2 * NN + n];
      q.w = 0.f;
      ((float4*)xyzT)[(size_t)b * NN + n] = q;
    }
#pragma unroll
    for (int r = 0; r < 16; ++r) {
      int c = g * 16 + r;
      tile[c][l] = feat[((size_t)b * NC + c) * NN + n0 + l];
    }
    __syncthreads();
#pragma unroll
    for (int r = 0; r < 16; ++r) {
      int nl = g * 16 + r;
      featF[((size_t)(b * NN + n0 + nl)) * NC + l] = (_Float16)tile[l][nl];
    }
    return;
  }

  // ---- FPS role ----
  const int b = bid;
  const int w = t >> 6;
  const float* X = xyz + (size_t)b * 3 * NN;
  float4* XL = (float4*)sm;                 // 32768 B
  uint2* ck = (uint2*)(sm + 32768);         // [2][4] = 64 B

  f32x2 px[4], py[4], pz[4], dist[4];
#pragma unroll
  for (int jj = 0; jj < 4; ++jj) {
    int n0 = t + 256 * jj, n1 = n0 + 1024;
    px[jj] = f32x2{X[n0], X[n1]};
    py[jj] = f32x2{X[NN + n0], X[NN + n1]};
    pz[jj] = f32x2{X[2 * NN + n0], X[2 * NN + n1]};
    dist[jj] = f32x2{1e10f, 1e10f};
    XL[n0] = make_float4(px[jj].x, py[jj].x, pz[jj].x, 0.f);
    XL[n1] = make_float4(px[jj].y, py[jj].y, pz[jj].y, 0.f);
  }
  float cx = X[0], cy = X[NN], cz = X[2 * NN];
  __syncthreads();
  int buf = 0;
  for (int i = 0; i < NP; ++i) {
    if (t == 0) {
      newxyz[b * 3 * NP + i] = cx;
      newxyz[b * 3 * NP + NP + i] = cy;
      newxyz[b * 3 * NP + 2 * NP + i] = cz;
    }
    const f32x2 ncx = f32x2{-cx, -cx}, ncy = f32x2{-cy, -cy}, ncz = f32x2{-cz, -cz};
    float hm[4];
#pragma unroll
    for (int jj = 0; jj < 4; ++jj) {
      f32x2 dx = pk_add(px[jj], ncx);
      f32x2 dy = pk_add(py[jj], ncy);
      f32x2 dz = pk_add(pz[jj], ncz);
      f32x2 s = pk_add(pk_add(pk_mul(dx, dx), pk_mul(dy, dy)), pk_mul(dz, dz));
      f32x2 d = dist[jj];
      d.x = fminf(d.x, s.x);
      d.y = fminf(d.y, s.y);
      dist[jj] = d;
      hm[jj] = fmaxf(d.x, d.y);
    }
    // phase A: wave max value (exact bits preserved by fmax chain)
    float m = fmaxf(fmaxf(hm[0], hm[1]), fmaxf(hm[2], hm[3]));
    m = dppmaxf<0x111>(m);
    m = dppmaxf<0x112>(m);
    m = dppmaxf<0x114>(m);
    m = dppmaxf<0x118>(m);
    m = dppmaxf<0x142>(m);
    m = dppmaxf<0x143>(m);
    const float vmax = __int_as_float(__builtin_amdgcn_readlane(__float_as_int(m), 63));
    // phase B: ballot per point-group, scalar first-set scan (min n)
    unsigned long long mm[8];
#pragma unroll
    for (int jj = 0; jj < 4; ++jj) {
      mm[jj] = __ballot(dist[jj].x == vmax);
      mm[4 + jj] = __ballot(dist[jj].y == vmax);
    }
    unsigned nw = 0;
#pragma unroll
    for (int q = 7; q >= 0; --q)
      if (mm[q]) nw = 256u * (unsigned)q + (unsigned)(w << 6) + (unsigned)__builtin_ctzll(mm[q]);
    if ((t & 63) == 0) ck[buf * 4 + w] = make_uint2(__float_as_uint(vmax), nw);
    __syncthreads();
    // cross-wave merge: 32B = two independent b128 reads, 3 lex compares.
    // dist >= 0 -> float order == unsigned order on the bits.
    uint4 c01 = *(const uint4*)&ck[buf * 4 + 0];
    uint4 c23 = *(const uint4*)&ck[buf * 4 + 2];
    unsigned v = c01.x, n = c01.y;
    if (c01.z > v || (c01.z == v && c01.w < n)) { v = c01.z; n = c01.w; }
    if (c23.x > v || (c23.x == v && c23.y < n)) { v = c23.x; n = c23.y; }
    if (c23.z > v || (c23.z == v && c23.w < n)) { v = c23.z; n = c23.w; }
    float4 c = XL[n];  // uniform address -> LDS broadcast
    cx = c.x;
    cy = c.y;
    cz = c.z;
    buf ^= 1;
  }
}

// ---------------------------------------------------------------------------
// MFMA MLP with fused ball query:
//  phase 0: one wave per s -> ball query (bit-exact ballot scan) into LDS idx
//  phase 1: gather hT[128 cols][96 k] from featF/xyzT via LDS idx
//  phase 2-4: 3 MFMA layers, f16 activations in LDS, fused maxpool.
// ---------------------------------------------------------------------------
#define HSTR 104   // hT stride in f16 (96 padded)
#define A1STR 72   // a1 stride (64 padded)
#define A2STR 136  // a2 stride (128 padded)
#define A1OFF 17408

__global__ __launch_bounds__(256) void mlp_kernel(
    const float* __restrict__ xyz, const float* __restrict__ xyzT,
    const _Float16* __restrict__ featF, const float* __restrict__ newxyz,
    const _Float16* __restrict__ W1f, const float* __restrict__ b1,
    const _Float16* __restrict__ W2f, const float* __restrict__ b2,
    const _Float16* __restrict__ W3f, const float* __restrict__ b3, float* __restrict__ out) {
  __shared__ _Float16 smem[17408 + 9216];  // 52 KB: h/a2 alias region + a1
  __shared__ int idx_l[4][32];
  __shared__ float cxyz[4][4];
  _Float16* hT = smem;
  _Float16* a1T = smem + A1OFF;
  const int b = blockIdx.x;
  const int s0 = blockIdx.y * 4;
  const int t = threadIdx.x;
  const int lane = t & 63, w = t >> 6;

  // ---- phase 0: ball query, one wave per s (identical FP ops -> bit-exact)
  {
    const float* X = xyz + (size_t)b * 3 * NN;
    const int sW = s0 + w;
    const float cxw = newxyz[b * 3 * NP + sW];
    const float cyw = newxyz[b * 3 * NP + NP + sW];
    const float czw = newxyz[b * 3 * NP + 2 * NP + sW];
    if (lane == 0) {
      cxyz[w][0] = cxw;
      cxyz[w][1] = cyw;
      cxyz[w][2] = czw;
    }
    const float r2 = (float)(0.2 * 0.2);
    int total = 0, first = 0;
    bool havefirst = false;
    for (int c0 = 0; c0 < NN; c0 += 64) {
      int n = c0 + lane;
      float d2 = sqdist(X[n] - cxw, X[NN + n] - cyw, X[2 * NN + n] - czw);
      bool hit = d2 < r2;
      unsigned long long mask = __ballot(hit);
      if (!havefirst && mask) {
        first = c0 + __builtin_ctzll(mask);
        havefirst = true;
      }
      if (hit) {
        int pos = total + (int)__popcll(mask & ((1ull << lane) - 1ull));
        if (pos < NS) idx_l[w][pos] = n;
      }
      total += (int)__popcll(mask);
      if (total >= NS) break;
    }
    if (total < NS && lane >= total && lane < NS) idx_l[w][lane] = first;
  }
  __syncthreads();

  // ---- phase 1: gather hT[128 cols][96 k] (k: 0..63 feat, 64..66 relxyz, 67..95 zero)
  {
    const int col = t & 127, hf = t >> 7;
    const int n = idx_l[col >> 5][col & 31];
    const _Float16* F = featF + (size_t)(b * NN + n) * NC;
#pragma unroll
    for (int j = 0; j < 4; ++j) {
      int p = hf * 4 + j;
      *(f16x8*)(&hT[col * HSTR + p * 8]) = *(const f16x8*)(F + p * 8);
    }
    if (hf == 0) {
      float4 pnt = ((const float4*)xyzT)[(size_t)b * NN + n];
      f16x8 v = {};
      v[0] = (_Float16)(pnt.x - cxyz[col >> 5][0]);
      v[1] = (_Float16)(pnt.y - cxyz[col >> 5][1]);
      v[2] = (_Float16)(pnt.z - cxyz[col >> 5][2]);
      *(f16x8*)(&hT[col * HSTR + 64]) = v;
    } else {
      f16x8 z = {};
      *(f16x8*)(&hT[col * HSTR + 72]) = z;
      *(f16x8*)(&hT[col * HSTR + 80]) = z;
      *(f16x8*)(&hT[col * HSTR + 88]) = z;
    }
  }
  __syncthreads();

  const int cl = lane & 15;  // A row / B col within tile
  const int kg = lane >> 4;  // k-group; D row group

  // ---- layer 1: K=96, O=64; wave w owns rows w*16..+15
  {
    f32x4 acc[8];
    {
      f32x4 bb = *(const f32x4*)(b1 + w * 16 + kg * 4);
#pragma unroll
      for (int ct = 0; ct < 8; ++ct) acc[ct] = bb;
    }
#pragma unroll
    for (int ks = 0; ks < 3; ++ks) {
      f16x8 A = *(const f16x8*)(W1f + (w * 16 + cl) * 96 + ks * 32 + kg * 8);
#pragma unroll
      for (int ct = 0; ct < 8; ++ct) {
        f16x8 B = *(const f16x8*)(&hT[(ct * 16 + cl) * HSTR + ks * 32 + kg * 8]);
        acc[ct] = __builtin_amdgcn_mfma_f32_16x16x32_f16(A, B, acc[ct], 0, 0, 0);
      }
    }
#pragma unroll
    for (int ct = 0; ct < 8; ++ct) {
      f16x4 v;
#pragma unroll
      for (int i2 = 0; i2 < 4; ++i2) v[i2] = (_Float16)fmaxf(acc[ct][i2], 0.f);
      *(f16x4*)(&a1T[(ct * 16 + cl) * A1STR + w * 16 + kg * 4]) = v;
    }
  }
  __syncthreads();

  // ---- layer 2: K=64, O=128; wave w owns rows w*32..+31 (a2 aliases h)
  {
    f32x4 acc[2][8];
#pragma unroll
    for (int r = 0; r < 2; ++r) {
      f32x4 bb = *(const f32x4*)(b2 + w * 32 + r * 16 + kg * 4);
#pragma unroll
      for (int ct = 0; ct < 8; ++ct) acc[r][ct] = bb;
    }
#pragma unroll
    for (int ks = 0; ks < 2; ++ks) {
      f16x8 A0 = *(const f16x8*)(W2f + (w * 32 + cl) * 64 + ks * 32 + kg * 8);
      f16x8 A1 = *(const f16x8*)(W2f + (w * 32 + 16 + cl) * 64 + ks * 32 + kg * 8);
#pragma unroll
      for (int ct = 0; ct < 8; ++ct) {
        f16x8 B = *(const f16x8*)(&a1T[(ct * 16 + cl) * A1STR + ks * 32 + kg * 8]);
        acc[0][ct] = __builtin_amdgcn_mfma_f32_16x16x32_f16(A0, B, acc[0][ct], 0, 0, 0);
        acc[1][ct] = __builtin_amdgcn_mfma_f32_16x16x32_f16(A1, B, acc[1][ct], 0, 0, 0);
      }
    }
#pragma unroll
    for (int r = 0; r < 2; ++r)
#pragma unroll
      for (int ct = 0; ct < 8; ++ct) {
        f16x4 v;
#pragma unroll
        for (int i2 = 0; i2 < 4; ++i2) v[i2] = (_Float16)fmaxf(acc[r][ct][i2], 0.f);
        *(f16x4*)(&hT[(ct * 16 + cl) * A2STR + w * 32 + r * 16 + kg * 4]) = v;
      }
  }
  __syncthreads();

  // ---- layer 3: K=128, O=256; wave w owns rows w*64..+63; fused maxpool
  float* out2 = out + NB * 3 * NP;
#pragma unroll
  for (int rh = 0; rh < 2; ++rh) {
    f32x4 acc[2][8];
#pragma unroll
    for (int r = 0; r < 2; ++r) {
      f32x4 bb = *(const f32x4*)(b3 + w * 64 + rh * 32 + r * 16 + kg * 4);
#pragma unroll
      for (int ct = 0; ct < 8; ++ct) acc[r][ct] = bb;
    }
#pragma unroll
    for (int ks = 0; ks < 4; ++ks) {
      f16x8 A0 = *(const f16x8*)(W3f + (w * 64 + rh * 32 + cl) * 128 + ks * 32 + kg * 8);
      f16x8 A1 = *(const f16x8*)(W3f + (w * 64 + rh * 32 + 16 + cl) * 128 + ks * 32 + kg * 8);
#pragma unroll
      for (int ct = 0; ct < 8; ++ct) {
        f16x8 B = *(const f16x8*)(&hT[(ct * 16 + cl) * A2STR + ks * 32 + kg * 8]);
        acc[0][ct] = __builtin_amdgcn_mfma_f32_16x16x32_f16(A0, B, acc[0][ct], 0, 0, 0);
        acc[1][ct] = __builtin_amdgcn_mfma_f32_16x16x32_f16(A1, B, acc[1][ct], 0, 0, 0);
      }
    }
#pragma unroll
    for (int r = 0; r < 2; ++r)
#pragma unroll
      for (int sl = 0; sl < 4; ++sl) {
        float vv[4];
#pragma unroll
        for (int i2 = 0; i2 < 4; ++i2) {
          float m0 = fmaxf(acc[r][sl * 2][i2], 0.f);
          float m1 = fmaxf(acc[r][sl * 2 + 1][i2], 0.f);
          float mv = fmaxf(m0, m1);
          mv = fmaxf(mv, __shfl_xor(mv, 1, 64));
          mv = fmaxf(mv, __shfl_xor(mv, 2, 64));
          mv = fmaxf(mv, __shfl_xor(mv, 4, 64));
          mv = fmaxf(mv, __shfl_xor(mv, 8, 64));
          vv[i2] = mv;
        }
        if (cl == 0) {
          int ob = w * 64 + rh * 32 + r * 16 + kg * 4;
#pragma unroll
          for (int i2 = 0; i2 < 4; ++i2)
            out2[((size_t)(b * 256 + ob + i2)) * NP + s0 + sl] = vv[i2];
        }
      }
  }
}

extern "C" void kernel_launch(void* const* d_in, const int* in_sizes, int n_in, void* d_out,
                              int out_size, void* d_ws, size_t ws_size, hipStream_t stream) {
  const float* xyz = (const float*)d_in[0];
  const float* feat = (const float*)d_in[1];
  const float* W1 = (const float*)d_in[2];
  const float* b1 = (const float*)d_in[3];
  const float* W2 = (const float*)d_in[4];
  const float* b2 = (const float*)d_in[5];
  const float* W3 = (const float*)d_in[6];
  const float* b3 = (const float*)d_in[7];
  float* out = (float*)d_out;
  char* ws = (char*)d_ws;
  float* xyzT = (float*)ws;                    // 512 KB
  _Float16* featF = (_Float16*)(ws + 524288);  // 4 MB
  _Float16* W1f = (_Float16*)(ws + 4718592);   // 12 KB
  _Float16* W2f = (_Float16*)(ws + 4730880);   // 16 KB
  _Float16* W3f = (_Float16*)(ws + 4747264);   // 64 KB

  hipLaunchKernelGGL(front_kernel, dim3(529), dim3(256), 0, stream, xyz, feat, W1, W2, W3, out,
                     featF, xyzT, W1f, W2f, W3f);
  hipLaunchKernelGGL(mlp_kernel, dim3(NB, 128), dim3(256), 0, stream, xyz, xyzT, featF, out, W1f,
                     b1, W2f, b2, W3f, b3, out);
}

// Round 9
// 334.225 us; speedup vs baseline: 1.1626x; 1.1626x over previous
//
#include <hip/hip_runtime.h>

#define NB 16
#define NN 2048
#define NP 512
#define NS 32
#define NC 64
#define NWORK 496

typedef _Float16 f16x8 __attribute__((ext_vector_type(8)));
typedef _Float16 f16x4 __attribute__((ext_vector_type(4)));
typedef float f32x4 __attribute__((ext_vector_type(4)));
typedef float f32x2 __attribute__((ext_vector_type(2)));

__device__ __forceinline__ float sqdist(float dx, float dy, float dz) {
  return __fadd_rn(__fadd_rn(__fmul_rn(dx, dx), __fmul_rn(dy, dy)), __fmul_rn(dz, dz));
}

__device__ __forceinline__ f32x2 pk_add(f32x2 a, f32x2 b) {
  f32x2 d;
  asm("v_pk_add_f32 %0, %1, %2" : "=v"(d) : "v"(a), "v"(b));
  return d;
}
__device__ __forceinline__ f32x2 pk_mul(f32x2 a, f32x2 b) {
  f32x2 d;
  asm("v_pk_mul_f32 %0, %1, %2" : "=v"(d) : "v"(a), "v"(b));
  return d;
}

template <int CTRL>
__device__ __forceinline__ float dppmaxf(float m) {
  int t = __builtin_amdgcn_update_dpp(0, __float_as_int(m), CTRL, 0xf, 0xf, true);
  return fmaxf(m, __int_as_float(t));  // 0-fill safe: all values >= 0
}

__device__ __forceinline__ unsigned ld_relax(const unsigned* p) {
  return __hip_atomic_load(p, __ATOMIC_RELAXED, __HIP_MEMORY_SCOPE_AGENT);
}
// bounded spin: relaxed polls + one final acquire (L1/L2 inv) once satisfied
__device__ __forceinline__ void waitge(const unsigned* p, unsigned need) {
  if (ld_relax(p) < need) {
    unsigned spins = 0;
    while (ld_relax(p) < need) {
      __builtin_amdgcn_s_sleep(8);
      if (++spins > (1u << 22)) break;  // safety valve (~0.9s) — never expected
    }
  }
  (void)__hip_atomic_load(p, __ATOMIC_ACQUIRE, __HIP_MEMORY_SCOPE_AGENT);
}

__global__ void init_kernel(unsigned* ctr) {
  if (threadIdx.x < 18) ctr[threadIdx.x * 16] = 0;  // 64B-strided counters
}

#define HSTR 104   // hT stride in f16 (96 padded)
#define A1STR 72   // a1 stride (64 padded)
#define A2STR 136  // a2 stride (128 padded)
#define A1OFF 17408

// ---------------------------------------------------------------------------
// Fused persistent kernel, 512 blocks (2/CU guaranteed: LDS 53.8KB, lb(256,2)):
//   blocks 0..15   : FPS producer (r8-proven), publishes progress every 64 iters
//   blocks 16..511 : prep/wconv -> stage gate -> item queue: (b,sg) ball+MFMA
// FPS blocks join the item queue after finishing. All cross-block data is
// gated by device-scope release/acquire (G16); ctr re-zeroed each call.
// ---------------------------------------------------------------------------
__global__ __launch_bounds__(256, 2) void fused_kernel(
    const float* __restrict__ xyz, const float* __restrict__ feat,
    const float* __restrict__ W1, const float* __restrict__ b1, const float* __restrict__ W2,
    const float* __restrict__ b2, const float* __restrict__ W3, const float* __restrict__ b3,
    float* __restrict__ out, _Float16* __restrict__ featF, float* __restrict__ xyzT,
    _Float16* __restrict__ W1f, _Float16* __restrict__ W2f, _Float16* __restrict__ W3f,
    unsigned* __restrict__ ctr) {
  __shared__ __align__(16) char sm[53824];
  __shared__ unsigned mitem;
  const int bid = blockIdx.x;
  const int t = threadIdx.x;
  float* newxyz = out;

  if (bid < NB) {
    // ================= FPS producer role =================
    const int b = bid;
    const int w = t >> 6;
    const float* X = xyz + (size_t)b * 3 * NN;
    float4* XL = (float4*)sm;           // 32768 B
    uint2* ck = (uint2*)(sm + 32768);   // 64 B

    f32x2 px[4], py[4], pz[4], dist[4];
#pragma unroll
    for (int jj = 0; jj < 4; ++jj) {
      int n0 = t + 256 * jj, n1 = n0 + 1024;
      px[jj] = f32x2{X[n0], X[n1]};
      py[jj] = f32x2{X[NN + n0], X[NN + n1]};
      pz[jj] = f32x2{X[2 * NN + n0], X[2 * NN + n1]};
      dist[jj] = f32x2{1e10f, 1e10f};
      XL[n0] = make_float4(px[jj].x, py[jj].x, pz[jj].x, 0.f);
      XL[n1] = make_float4(px[jj].y, py[jj].y, pz[jj].y, 0.f);
    }
    float cx = X[0], cy = X[NN], cz = X[2 * NN];
    __syncthreads();
    int buf = 0;
    for (int i = 0; i < NP; ++i) {
      if (t == 0) {
        // device-scope relaxed stores -> data reaches shared L3 (cross-XCD)
        __hip_atomic_store(&newxyz[b * 3 * NP + i], cx, __ATOMIC_RELAXED,
                           __HIP_MEMORY_SCOPE_AGENT);
        __hip_atomic_store(&newxyz[b * 3 * NP + NP + i], cy, __ATOMIC_RELAXED,
                           __HIP_MEMORY_SCOPE_AGENT);
        __hip_atomic_store(&newxyz[b * 3 * NP + 2 * NP + i], cz, __ATOMIC_RELAXED,
                           __HIP_MEMORY_SCOPE_AGENT);
        if ((i & 63) == 63)  // publish (release: belt-and-braces visibility)
          __hip_atomic_store(&ctr[b * 16], (unsigned)(i + 1), __ATOMIC_RELEASE,
                             __HIP_MEMORY_SCOPE_AGENT);
      }
      const f32x2 ncx = f32x2{-cx, -cx}, ncy = f32x2{-cy, -cy}, ncz = f32x2{-cz, -cz};
      float hm[4];
#pragma unroll
      for (int jj = 0; jj < 4; ++jj) {
        f32x2 dx = pk_add(px[jj], ncx);
        f32x2 dy = pk_add(py[jj], ncy);
        f32x2 dz = pk_add(pz[jj], ncz);
        f32x2 s = pk_add(pk_add(pk_mul(dx, dx), pk_mul(dy, dy)), pk_mul(dz, dz));
        f32x2 d = dist[jj];
        d.x = fminf(d.x, s.x);
        d.y = fminf(d.y, s.y);
        dist[jj] = d;
        hm[jj] = fmaxf(d.x, d.y);
      }
      float m = fmaxf(fmaxf(hm[0], hm[1]), fmaxf(hm[2], hm[3]));
      m = dppmaxf<0x111>(m);
      m = dppmaxf<0x112>(m);
      m = dppmaxf<0x114>(m);
      m = dppmaxf<0x118>(m);
      m = dppmaxf<0x142>(m);
      m = dppmaxf<0x143>(m);
      const float vmax = __int_as_float(__builtin_amdgcn_readlane(__float_as_int(m), 63));
      unsigned long long mm[8];
#pragma unroll
      for (int jj = 0; jj < 4; ++jj) {
        mm[jj] = __ballot(dist[jj].x == vmax);
        mm[4 + jj] = __ballot(dist[jj].y == vmax);
      }
      unsigned nw = 0;
#pragma unroll
      for (int q = 7; q >= 0; --q)
        if (mm[q]) nw = 256u * (unsigned)q + (unsigned)(w << 6) + (unsigned)__builtin_ctzll(mm[q]);
      if ((t & 63) == 0) ck[buf * 4 + w] = make_uint2(__float_as_uint(vmax), nw);
      __syncthreads();
      uint4 c01 = *(const uint4*)&ck[buf * 4 + 0];
      uint4 c23 = *(const uint4*)&ck[buf * 4 + 2];
      unsigned v = c01.x, n = c01.y;
      if (c01.z > v || (c01.z == v && c01.w < n)) { v = c01.z; n = c01.w; }
      if (c23.x > v || (c23.x == v && c23.y < n)) { v = c23.x; n = c23.y; }
      if (c23.z > v || (c23.z == v && c23.w < n)) { v = c23.z; n = c23.w; }
      float4 c = XL[n];
      cx = c.x;
      cy = c.y;
      cz = c.z;
      buf ^= 1;
    }
  } else {
    // ================= worker role: prep + wconv, then stage release =======
    const int wid = bid - NB;
    for (int rep = 0; rep < 2; ++rep) {
      int p = wid + rep * NWORK;
      if (p >= 512) break;
      float(*tile)[65] = (float(*)[65])sm;
      const int b = p >> 5;
      const int n0 = (p & 31) * 64;
      const int g = t >> 6, l = t & 63;
      if (g == 0) {
        int n = n0 + l;
        float4 q;
        q.x = xyz[(size_t)b * 3 * NN + n];
        q.y = xyz[(size_t)b * 3 * NN + NN + n];
        q.z = xyz[(size_t)b * 3 * NN + 2 * NN + n];
        q.w = 0.f;
        ((float4*)xyzT)[(size_t)b * NN + n] = q;
      }
      __syncthreads();  // tile reuse across reps
#pragma unroll
      for (int r = 0; r < 16; ++r) {
        int c = g * 16 + r;
        tile[c][l] = feat[((size_t)b * NC + c) * NN + n0 + l];
      }
      __syncthreads();
#pragma unroll
      for (int r = 0; r < 16; ++r) {
        int nl = g * 16 + r;
        featF[((size_t)(b * NN + n0 + nl)) * NC + l] = (_Float16)tile[l][nl];
      }
    }
    if (wid == 31) {
      for (int i = t; i < 256 * 128; i += 256) {
        if (i < 64 * 96) {
          int o = i / 96, k = i - o * 96;
          float v = (k < 64) ? W1[o * 67 + 3 + k] : ((k < 67) ? W1[o * 67 + (k - 64)] : 0.f);
          W1f[i] = (_Float16)v;
        }
        if (i < 128 * 64) W2f[i] = (_Float16)W2[i];
        W3f[i] = (_Float16)W3[i];
      }
    }
    __syncthreads();  // all waves' stores drained (vmcnt before barrier)
    if (t == 0)
      (void)__hip_atomic_fetch_add(&ctr[16 * 16], 1u, __ATOMIC_RELEASE,
                                   __HIP_MEMORY_SCOPE_AGENT);
  }

  // ================= stage gate, then item queue =================
  if (t == 0) waitge(&ctr[16 * 16], NWORK);
  __syncthreads();

  _Float16* hT = (_Float16*)sm;
  _Float16* a1T = (_Float16*)(sm) + A1OFF;
  int(*idx_l)[32] = (int(*)[32])(sm + 53248);
  float(*cxyz)[4] = (float(*)[4])(sm + 53760);
  const int lane = t & 63, w = t >> 6;
  const int cl = lane & 15;
  const int kg = lane >> 4;
  float* out2 = out + NB * 3 * NP;

  for (;;) {
    if (t == 0)
      mitem = __hip_atomic_fetch_add(&ctr[17 * 16], 1u, __ATOMIC_RELAXED,
                                     __HIP_MEMORY_SCOPE_AGENT);
    __syncthreads();
    const unsigned m = mitem;
    if (m >= (unsigned)(NB * 128)) break;
    const int b = (int)(m & 15u);
    const int sg = (int)(m >> 4);
    const int s0 = sg * 4;
    if (t == 0) waitge(&ctr[b * 16], (unsigned)(s0 + 4));
    __syncthreads();

    // ---- phase 0: ball query, one wave per s (bit-exact ballot scan)
    {
      const float* X = xyz + (size_t)b * 3 * NN;
      const int sW = s0 + w;
      const float cxw = newxyz[b * 3 * NP + sW];
      const float cyw = newxyz[b * 3 * NP + NP + sW];
      const float czw = newxyz[b * 3 * NP + 2 * NP + sW];
      if (lane == 0) {
        cxyz[w][0] = cxw;
        cxyz[w][1] = cyw;
        cxyz[w][2] = czw;
      }
      const float r2 = (float)(0.2 * 0.2);
      int total = 0, first = 0;
      bool havefirst = false;
      for (int c0 = 0; c0 < NN; c0 += 64) {
        int n = c0 + lane;
        float d2 = sqdist(X[n] - cxw, X[NN + n] - cyw, X[2 * NN + n] - czw);
        bool hit = d2 < r2;
        unsigned long long mask = __ballot(hit);
        if (!havefirst && mask) {
          first = c0 + __builtin_ctzll(mask);
          havefirst = true;
        }
        if (hit) {
          int pos = total + (int)__popcll(mask & ((1ull << lane) - 1ull));
          if (pos < NS) idx_l[w][pos] = n;
        }
        total += (int)__popcll(mask);
        if (total >= NS) break;
      }
      if (total < NS && lane >= total && lane < NS) idx_l[w][lane] = first;
    }
    __syncthreads();

    // ---- phase 1: gather hT[128 cols][96 k]
    {
      const int col = t & 127, hf = t >> 7;
      const int n = idx_l[col >> 5][col & 31];
      const _Float16* F = featF + (size_t)(b * NN + n) * NC;
#pragma unroll
      for (int j = 0; j < 4; ++j) {
        int p = hf * 4 + j;
        *(f16x8*)(&hT[col * HSTR + p * 8]) = *(const f16x8*)(F + p * 8);
      }
      if (hf == 0) {
        float4 pnt = ((const float4*)xyzT)[(size_t)b * NN + n];
        f16x8 v = {};
        v[0] = (_Float16)(pnt.x - cxyz[col >> 5][0]);
        v[1] = (_Float16)(pnt.y - cxyz[col >> 5][1]);
        v[2] = (_Float16)(pnt.z - cxyz[col >> 5][2]);
        *(f16x8*)(&hT[col * HSTR + 64]) = v;
      } else {
        f16x8 z = {};
        *(f16x8*)(&hT[col * HSTR + 72]) = z;
        *(f16x8*)(&hT[col * HSTR + 80]) = z;
        *(f16x8*)(&hT[col * HSTR + 88]) = z;
      }
    }
    __syncthreads();

    // ---- layer 1: K=96, O=64
    {
      f32x4 acc[8];
      {
        f32x4 bb = *(const f32x4*)(b1 + w * 16 + kg * 4);
#pragma unroll
        for (int ct = 0; ct < 8; ++ct) acc[ct] = bb;
      }
#pragma unroll
      for (int ks = 0; ks < 3; ++ks) {
        f16x8 A = *(const f16x8*)(W1f + (w * 16 + cl) * 96 + ks * 32 + kg * 8);
#pragma unroll
        for (int ct = 0; ct < 8; ++ct) {
          f16x8 B = *(const f16x8*)(&hT[(ct * 16 + cl) * HSTR + ks * 32 + kg * 8]);
          acc[ct] = __builtin_amdgcn_mfma_f32_16x16x32_f16(A, B, acc[ct], 0, 0, 0);
        }
      }
#pragma unroll
      for (int ct = 0; ct < 8; ++ct) {
        f16x4 v;
#pragma unroll
        for (int i2 = 0; i2 < 4; ++i2) v[i2] = (_Float16)fmaxf(acc[ct][i2], 0.f);
        *(f16x4*)(&a1T[(ct * 16 + cl) * A1STR + w * 16 + kg * 4]) = v;
      }
    }
    __syncthreads();

    // ---- layer 2: K=64, O=128 (a2 aliases hT)
    {
      f32x4 acc[2][8];
#pragma unroll
      for (int r = 0; r < 2; ++r) {
        f32x4 bb = *(const f32x4*)(b2 + w * 32 + r * 16 + kg * 4);
#pragma unroll
        for (int ct = 0; ct < 8; ++ct) acc[r][ct] = bb;
      }
#pragma unroll
      for (int ks = 0; ks < 2; ++ks) {
        f16x8 A0 = *(const f16x8*)(W2f + (w * 32 + cl) * 64 + ks * 32 + kg * 8);
        f16x8 A1 = *(const f16x8*)(W2f + (w * 32 + 16 + cl) * 64 + ks * 32 + kg * 8);
#pragma unroll
        for (int ct = 0; ct < 8; ++ct) {
          f16x8 B = *(const f16x8*)(&a1T[(ct * 16 + cl) * A1STR + ks * 32 + kg * 8]);
          acc[0][ct] = __builtin_amdgcn_mfma_f32_16x16x32_f16(A0, B, acc[0][ct], 0, 0, 0);
          acc[1][ct] = __builtin_amdgcn_mfma_f32_16x16x32_f16(A1, B, acc[1][ct], 0, 0, 0);
        }
      }
#pragma unroll
      for (int r = 0; r < 2; ++r)
#pragma unroll
        for (int ct = 0; ct < 8; ++ct) {
          f16x4 v;
#pragma unroll
          for (int i2 = 0; i2 < 4; ++i2) v[i2] = (_Float16)fmaxf(acc[r][ct][i2], 0.f);
          *(f16x4*)(&hT[(ct * 16 + cl) * A2STR + w * 32 + r * 16 + kg * 4]) = v;
        }
    }
    __syncthreads();

    // ---- layer 3: K=128, O=256; fused maxpool
#pragma unroll
    for (int rh = 0; rh < 2; ++rh) {
      f32x4 acc[2][8];
#pragma unroll
      for (int r = 0; r < 2; ++r) {
        f32x4 bb = *(const f32x4*)(b3 + w * 64 + rh * 32 + r * 16 + kg * 4);
#pragma unroll
        for (int ct = 0; ct < 8; ++ct) acc[r][ct] = bb;
      }
#pragma unroll
      for (int ks = 0; ks < 4; ++ks) {
        f16x8 A0 = *(const f16x8*)(W3f + (w * 64 + rh * 32 + cl) * 128 + ks * 32 + kg * 8);
        f16x8 A1 = *(const f16x8*)(W3f + (w * 64 + rh * 32 + 16 + cl) * 128 + ks * 32 + kg * 8);
#pragma unroll
        for (int ct = 0; ct < 8; ++ct) {
          f16x8 B = *(const f16x8*)(&hT[(ct * 16 + cl) * A2STR + ks * 32 + kg * 8]);
          acc[0][ct] = __builtin_amdgcn_mfma_f32_16x16x32_f16(A0, B, acc[0][ct], 0, 0, 0);
          acc[1][ct] = __builtin_amdgcn_mfma_f32_16x16x32_f16(A1, B, acc[1][ct], 0, 0, 0);
        }
      }
#pragma unroll
      for (int r = 0; r < 2; ++r)
#pragma unroll
        for (int sl = 0; sl < 4; ++sl) {
          float vv[4];
#pragma unroll
          for (int i2 = 0; i2 < 4; ++i2) {
            float m0 = fmaxf(acc[r][sl * 2][i2], 0.f);
            float m1 = fmaxf(acc[r][sl * 2 + 1][i2], 0.f);
            float mv = fmaxf(m0, m1);
            mv = fmaxf(mv, __shfl_xor(mv, 1, 64));
            mv = fmaxf(mv, __shfl_xor(mv, 2, 64));
            mv = fmaxf(mv, __shfl_xor(mv, 4, 64));
            mv = fmaxf(mv, __shfl_xor(mv, 8, 64));
            vv[i2] = mv;
          }
          if (cl == 0) {
            int ob = w * 64 + rh * 32 + r * 16 + kg * 4;
#pragma unroll
            for (int i2 = 0; i2 < 4; ++i2)
              out2[((size_t)(b * 256 + ob + i2)) * NP + s0 + sl] = vv[i2];
          }
        }
    }
    __syncthreads();  // LDS + mitem reuse protection
  }
}

extern "C" void kernel_launch(void* const* d_in, const int* in_sizes, int n_in, void* d_out,
                              int out_size, void* d_ws, size_t ws_size, hipStream_t stream) {
  const float* xyz = (const float*)d_in[0];
  const float* feat = (const float*)d_in[1];
  const float* W1 = (const float*)d_in[2];
  const float* b1 = (const float*)d_in[3];
  const float* W2 = (const float*)d_in[4];
  const float* b2 = (const float*)d_in[5];
  const float* W3 = (const float*)d_in[6];
  const float* b3 = (const float*)d_in[7];
  float* out = (float*)d_out;
  char* ws = (char*)d_ws;
  float* xyzT = (float*)ws;                    // 512 KB
  _Float16* featF = (_Float16*)(ws + 524288);  // 4 MB
  _Float16* W1f = (_Float16*)(ws + 4718592);   // 12 KB
  _Float16* W2f = (_Float16*)(ws + 4730880);   // 16 KB
  _Float16* W3f = (_Float16*)(ws + 4747264);   // 64 KB
  unsigned* ctr = (unsigned*)(ws + 4812800);   // 18 x 64B counters

  hipLaunchKernelGGL(init_kernel, dim3(1), dim3(64), 0, stream, ctr);
  hipLaunchKernelGGL(fused_kernel, dim3(512), dim3(256), 0, stream, xyz, feat, W1, b1, W2, b2, W3,
                     b3, out, featF, xyzT, W1f, W2f, W3f, ctr);
}